// Round 2
// baseline (559.640 us; speedup 1.0000x reference)
//
#include <hip/hip_runtime.h>

// NormConv2d: depthwise 3x3 correlation with L2-normalized filters, divided by
// per-patch L2 norm. x: (16,3,1024,1024) fp32, w: (3,1,3,3) fp32, zero-pad 1.
//
// Round 4 = Round 3 with the nontemporal-store compile fix.
// Round 3 theory: rocprof showed the round-2 kernel at 121.5us with only
// 1.66 TB/s write BW (21% peak) and 44 VGPRs: the rotating 3-row window
// loaded row y+1 and consumed it in the SAME iteration (prefetch distance 0)
// -> HBM-latency-bound, not BW-bound.
// Changes vs round 2:
//  - 7-slot rotating row buffer: prologue issues 6 row-loads; iteration i
//    issues the load for row i+5 (consumed 4 iterations later). ~4-5 row
//    loads in flight per wave instead of ~1.
//  - ROWS 8->16: halo fetch ratio 18/16 = 1.125x (was 1.25x).
//  - colsq[] reuse across the 4 output columns (~13% fewer VALU ops).
//  - nontemporal stores via native ext_vector_type (HIP float4 is rejected
//    by __builtin_nontemporal_store): output is write-once, keep L2 for
//    input halos.
// XCD swizzle unchanged: same (blockIdx & 7) == same XCD under round-robin
// dispatch, mapped to contiguous logical tiles so halo rows hit that XCD's L2.

#define HH 1024
#define WW 1024
#define CC 3
#define NN 16
#define ROWS 16
#define TILES (HH / ROWS)        // 64 tiles per plane
#define NBLK (NN * CC * TILES)   // 3072 blocks (12 per CU, uniform)
#define SLOTS 7                  // rotating row-buffer depth

typedef float f32x4 __attribute__((ext_vector_type(4)));

__device__ __forceinline__ void load_row(const float* __restrict__ base, int y,
                                         int x0, float* __restrict__ dst)
{
    if ((unsigned)y >= (unsigned)HH) {   // zero-pad top/bottom (block-uniform)
#pragma unroll
        for (int k = 0; k < 6; ++k) dst[k] = 0.f;
    } else {
        const float* p = base + y * WW;
        const float4 c4 = *(const float4*)(p + x0);       // 16B-aligned
        dst[0] = (x0 > 0)      ? p[x0 - 1] : 0.f;         // left halo (L1 hit)
        dst[1] = c4.x; dst[2] = c4.y; dst[3] = c4.z; dst[4] = c4.w;
        dst[5] = (x0 + 4 < WW) ? p[x0 + 4] : 0.f;         // right halo
    }
}

__global__ __launch_bounds__(256, 5) void normconv_kernel(
    const float* __restrict__ x, const float* __restrict__ w, float* __restrict__ out)
{
    // XCD-aware swizzle: logical tile L from physical block id b such that
    // blocks with equal (b & 7) cover a contiguous range of L.
    const int b     = blockIdx.x;
    const int L     = (b & 7) * (NBLK / 8) + (b >> 3);
    const int tile  = L & (TILES - 1);
    const int plane = L / TILES;
    const int c     = plane % CC;

    // Normalized weights — block-uniform, scalarized by the compiler
    float wn[9];
    float s = 0.f;
#pragma unroll
    for (int i = 0; i < 9; ++i) { float wi = w[c * 9 + i]; wn[i] = wi; s += wi * wi; }
    const float winv = rsqrtf(s);
#pragma unroll
    for (int i = 0; i < 9; ++i) wn[i] *= winv;

    const int x0 = threadIdx.x << 2;                 // 4 outputs per thread
    const int y0 = tile * ROWS;
    const float* base  = x   + (size_t)plane * (HH * WW);
    float*       obase = out + (size_t)plane * (HH * WW);

    // Rotating SLOTS-deep row window: slot (r+1) % SLOTS holds input row y0+r,
    // v[s][0..5] = cols x0-1 .. x0+4.
    float v[SLOTS][6];
#pragma unroll
    for (int r = -1; r <= 4; ++r)                    // 6 loads in flight
        load_row(base, y0 + r, x0, v[r + 1]);

#pragma unroll
    for (int i = 0; i < ROWS; ++i) {
        // Prefetch row i+5 into the slot freed by row i-2 (dead since iter i-1).
        // Consumed as r2 at iteration i+4 -> distance-4 pipeline.
        if (i + 5 <= ROWS)                           // compile-time predicate
            load_row(base, y0 + i + 5, x0, v[(i + 6) % SLOTS]);

        const float* r0 = v[(i + 0) % SLOTS];        // row i-1
        const float* r1 = v[(i + 1) % SLOTS];        // row i
        const float* r2 = v[(i + 2) % SLOTS];        // row i+1

        // Per-column sum of squares, shared by the 3 windows that touch it.
        float colsq[6];
#pragma unroll
        for (int t = 0; t < 6; ++t)
            colsq[t] = r0[t] * r0[t] + r1[t] * r1[t] + r2[t] * r2[t];

        f32x4 o;
#pragma unroll
        for (int j = 0; j < 4; ++j) {
            float num = 0.f;
#pragma unroll
            for (int k = 0; k < 3; ++k)
                num += r0[j + k] * wn[k] + r1[j + k] * wn[3 + k] + r2[j + k] * wn[6 + k];
            const float sq = colsq[j] + colsq[j + 1] + colsq[j + 2];
            o[j] = num * rsqrtf(sq);
        }
        __builtin_nontemporal_store(o, (f32x4*)(obase + (size_t)(y0 + i) * WW + x0));
    }
}

extern "C" void kernel_launch(void* const* d_in, const int* in_sizes, int n_in,
                              void* d_out, int out_size, void* d_ws, size_t ws_size,
                              hipStream_t stream) {
    const float* x = (const float*)d_in[0];
    const float* w = (const float*)d_in[1];
    float* out = (float*)d_out;

    normconv_kernel<<<NBLK, 256, 0, stream>>>(x, w, out);
}

// Round 4
// 348.956 us; speedup vs baseline: 1.6038x; 1.6038x over previous
//
#include <hip/hip_runtime.h>

// NormConv2d: depthwise 3x3 correlation with L2-normalized filters, divided by
// per-patch L2 norm. x: (16,3,1024,1024) fp32, w: (3,1,3,3) fp32, zero-pad 1.
//
// Round 6 = Round 5 resubmitted (bench infra failed; no kernel signal).
// Round 5: registerize the pipeline. Round-4's v[SLOTS][6] circular buffer
// with %SLOTS indexing was NOT promoted to VGPRs (VGPR_Count=48, scratch
// traffic: WRITE 478MB vs 201MB output, FETCH 488MB vs 226MB ideal,
// occupancy 50%) -> every "register" row was a scratch round-trip, 345us.
// Fix: SIX NAMED row buffers sA..sF, rotated by a macro-expanded 16-step
// schedule (period-6). Every index is a compile-time constant -> SROA puts
// all slots in VGPRs. Prefetch distance 3: row I+4 issued at step I,
// consumed at step I+3 (~3 row-loads = 9 VMEM in flight per wave).
//  - ROWS=16: halo fetch ratio 18/16 = 1.125x.
//  - colsq[] reuse across the 4 output columns.
//  - nontemporal stores (ext_vector type): output is write-once; if
//    WRITE_SIZE stays >201MB next round, the NT store is the amplifier.
// XCD swizzle: same (blockIdx & 7) == same XCD under round-robin dispatch,
// mapped to contiguous logical tiles so halo rows hit that XCD's L2.

#define HH 1024
#define WW 1024
#define CC 3
#define NN 16
#define ROWS 16
#define TILES (HH / ROWS)        // 64 tiles per plane
#define NBLK (NN * CC * TILES)   // 3072 blocks (12 per CU, uniform)

typedef float f32x4 __attribute__((ext_vector_type(4)));

__device__ __forceinline__ void load_row(const float* __restrict__ base, int y,
                                         int x0, float* __restrict__ dst)
{
    if ((unsigned)y >= (unsigned)HH) {   // zero-pad top/bottom (block-uniform)
#pragma unroll
        for (int k = 0; k < 6; ++k) dst[k] = 0.f;
    } else {
        const float* p = base + y * WW;
        const float4 c4 = *(const float4*)(p + x0);       // 16B-aligned
        dst[0] = (x0 > 0)      ? p[x0 - 1] : 0.f;         // left halo (L1 hit)
        dst[1] = c4.x; dst[2] = c4.y; dst[3] = c4.z; dst[4] = c4.w;
        dst[5] = (x0 + 4 < WW) ? p[x0 + 4] : 0.f;         // right halo
    }
}

__device__ __forceinline__ void compute_store_row(
    const float* __restrict__ r0, const float* __restrict__ r1,
    const float* __restrict__ r2, const float* __restrict__ wn,
    float* __restrict__ orow, int x0)
{
    // Per-column sum of squares, shared by the 3 windows that touch it.
    float colsq[6];
#pragma unroll
    for (int t = 0; t < 6; ++t)
        colsq[t] = r0[t] * r0[t] + r1[t] * r1[t] + r2[t] * r2[t];

    f32x4 o;
#pragma unroll
    for (int j = 0; j < 4; ++j) {
        float num = 0.f;
#pragma unroll
        for (int k = 0; k < 3; ++k)
            num += r0[j + k] * wn[k] + r1[j + k] * wn[3 + k] + r2[j + k] * wn[6 + k];
        const float sq = colsq[j] + colsq[j + 1] + colsq[j + 2];
        o[j] = num * rsqrtf(sq);
    }
    __builtin_nontemporal_store(o, (f32x4*)(orow + x0));
}

__global__ __launch_bounds__(256, 4) void normconv_kernel(
    const float* __restrict__ x, const float* __restrict__ w, float* __restrict__ out)
{
    // XCD-aware swizzle: logical tile L from physical block id b such that
    // blocks with equal (b & 7) cover a contiguous range of L.
    const int b     = blockIdx.x;
    const int L     = (b & 7) * (NBLK / 8) + (b >> 3);
    const int tile  = L & (TILES - 1);
    const int plane = L / TILES;
    const int c     = plane % CC;

    // Normalized weights — block-uniform, scalarized by the compiler
    float wn[9];
    float s = 0.f;
#pragma unroll
    for (int i = 0; i < 9; ++i) { float wi = w[c * 9 + i]; wn[i] = wi; s += wi * wi; }
    const float winv = rsqrtf(s);
#pragma unroll
    for (int i = 0; i < 9; ++i) wn[i] *= winv;

    const int x0 = threadIdx.x << 2;                 // 4 outputs per thread
    const int y0 = tile * ROWS;
    const float* base  = x   + (size_t)plane * (HH * WW);
    float*       obase = out + (size_t)plane * (HH * WW);

    // Six NAMED slots (period-6 rotation), all constant-indexed -> VGPRs.
    // Slot s* holds cols x0-1 .. x0+4 of one input row.
    float sA[6], sB[6], sC[6], sD[6], sE[6], sF[6];
    load_row(base, y0 - 1, x0, sA);                  // 5 loads in flight
    load_row(base, y0 + 0, x0, sB);
    load_row(base, y0 + 1, x0, sC);
    load_row(base, y0 + 2, x0, sD);
    load_row(base, y0 + 3, x0, sE);

    // Step I: prefetch input row y0+I+4 into the slot holding dead row I-2,
    // then compute output row y0+I from rows I-1, I, I+1 (distance-3 pipe).
#define STEP(I, R0, R1, R2, PF)                                                \
    do {                                                                       \
        if ((I) + 4 <= ROWS) load_row(base, y0 + (I) + 4, x0, PF);             \
        compute_store_row(R0, R1, R2, wn, obase + (size_t)(y0 + (I)) * WW, x0);\
    } while (0)

    STEP(0,  sA, sB, sC, sF);
    STEP(1,  sB, sC, sD, sA);
    STEP(2,  sC, sD, sE, sB);
    STEP(3,  sD, sE, sF, sC);
    STEP(4,  sE, sF, sA, sD);
    STEP(5,  sF, sA, sB, sE);
    STEP(6,  sA, sB, sC, sF);
    STEP(7,  sB, sC, sD, sA);
    STEP(8,  sC, sD, sE, sB);
    STEP(9,  sD, sE, sF, sC);
    STEP(10, sE, sF, sA, sD);
    STEP(11, sF, sA, sB, sE);
    STEP(12, sA, sB, sC, sF);
    STEP(13, sB, sC, sD, sA);
    STEP(14, sC, sD, sE, sB);
    STEP(15, sD, sE, sF, sC);
#undef STEP
}

extern "C" void kernel_launch(void* const* d_in, const int* in_sizes, int n_in,
                              void* d_out, int out_size, void* d_ws, size_t ws_size,
                              hipStream_t stream) {
    const float* x = (const float*)d_in[0];
    const float* w = (const float*)d_in[1];
    float* out = (float*)d_out;

    normconv_kernel<<<NBLK, 256, 0, stream>>>(x, w, out);
}